// Round 1
// 581.128 us; speedup vs baseline: 1.3254x; 1.3254x over previous
//
#include <hip/hip_runtime.h>
#include <hip/hip_bf16.h>

// ---------------- problem constants ----------------
constexpr int NN = 50000;     // nodes
constexpr int NE = 400000;    // edges (without self loops)
constexpr int NE2 = NE + NN;  // with self loops
constexpr float NEG_SLOPE = 0.2f;

typedef __attribute__((ext_vector_type(8))) __bf16 bf16x8;
typedef __attribute__((ext_vector_type(4))) float f32x4;

__device__ inline float bf2f(unsigned short u) { return __uint_as_float(((unsigned)u) << 16); }
__device__ inline unsigned short f2bf(float f) {
    unsigned x = __float_as_uint(f);
    return (unsigned short)((x + 0x7fffu + ((x >> 16) & 1u)) >> 16);  // RNE
}

__device__ inline void gload16(const unsigned short* g, unsigned short* l) {
    // async global->LDS, 16B per lane; LDS dest is wave-uniform base + lane*16
    __builtin_amdgcn_global_load_lds(
        (const __attribute__((address_space(1))) unsigned int*)(g),
        (__attribute__((address_space(3))) unsigned int*)(l), 16, 0, 0);
}

// ---------------- CSR build ----------------
__global__ void count_deg(const int* __restrict__ ei, int* __restrict__ deg) {
    int e = blockIdx.x * blockDim.x + threadIdx.x;
    if (e >= NE2) return;
    int dst = (e < NE) ? ei[NE + e] : (e - NE);
    atomicAdd(&deg[dst], 1);
}

__global__ __launch_bounds__(1024) void scan_deg(const int* __restrict__ deg,
                                                 int* __restrict__ row_ptr,
                                                 int* __restrict__ cursor) {
    __shared__ int wsum[16];
    int t = threadIdx.x, lane = t & 63, w = t >> 6;
    int carry = 0;
    for (int base = 0; base < NN; base += 1024) {
        int i = base + t;
        int v = (i < NN) ? deg[i] : 0;
        int x = v;
        #pragma unroll
        for (int off = 1; off < 64; off <<= 1) {
            int y = __shfl_up(x, off);
            if (lane >= off) x += y;
        }
        if (lane == 63) wsum[w] = x;
        __syncthreads();
        if (w == 0 && lane < 16) {
            int s = wsum[lane];
            #pragma unroll
            for (int off = 1; off < 16; off <<= 1) {
                int y = __shfl_up(s, off);
                if (lane >= off) s += y;
            }
            wsum[lane] = s;
        }
        __syncthreads();
        int woff = (w == 0) ? 0 : wsum[w - 1];
        int incl = x + woff;
        if (i < NN) {
            int excl = carry + incl - v;
            row_ptr[i] = excl;
            cursor[i] = excl;
        }
        carry += wsum[15];
        __syncthreads();
    }
    if (t == 0) row_ptr[NN] = carry;
}

__global__ void scatter_edges(const int* __restrict__ ei, int* __restrict__ cursor,
                              int* __restrict__ csr_src) {
    int e = blockIdx.x * blockDim.x + threadIdx.x;
    if (e >= NE2) return;
    int src, dst;
    if (e < NE) { src = ei[e]; dst = ei[NE + e]; }
    else        { src = dst = e - NE; }
    int pos = atomicAdd(&cursor[dst], 1);
    csr_src[pos] = src;
}

// ---------------- fp32 -> bf16 convert (x) ----------------
__global__ void f32_to_bf16(const float* __restrict__ in, unsigned short* __restrict__ out, int n4) {
    int i = blockIdx.x * blockDim.x + threadIdx.x;
    if (i >= n4) return;
    float4 v = *(const float4*)(in + 4 * (size_t)i);
    ushort4 o;
    o.x = f2bf(v.x); o.y = f2bf(v.y); o.z = f2bf(v.z); o.w = f2bf(v.w);
    *(ushort4*)(out + 4 * (size_t)i) = o;
}

// ---------------- one-shot weight conversion: all 8 W matrices -> bf16, concatenated ----------------
// Layout (bf16 elems): [W0l 32768][W0r 32768][W1l 65536][W1r 65536][W2l 65536][W2r 65536][W3l 32768][W3r 32768]
// Per layer this is Wcat[2*hc][K] with Wl rows first, Wr rows after -> fused GEMM reads it directly.
__global__ void conv_weights(const float* __restrict__ w0l, const float* __restrict__ w0r,
                             const float* __restrict__ w1l, const float* __restrict__ w1r,
                             const float* __restrict__ w2l, const float* __restrict__ w2r,
                             const float* __restrict__ w3l, const float* __restrict__ w3r,
                             unsigned short* __restrict__ out) {
    int i = blockIdx.x * blockDim.x + threadIdx.x;  // float4 index, 0..98303
    const float* src; int base;
    if      (i < 8192)  { src = w0l; base = 0; }
    else if (i < 16384) { src = w0r; base = 8192; }
    else if (i < 32768) { src = w1l; base = 16384; }
    else if (i < 49152) { src = w1r; base = 32768; }
    else if (i < 65536) { src = w2l; base = 49152; }
    else if (i < 81920) { src = w2r; base = 65536; }
    else if (i < 90112) { src = w3l; base = 81920; }
    else                { src = w3r; base = 90112; }
    float4 v = ((const float4*)src)[i - base];
    ushort4 o;
    o.x = f2bf(v.x); o.y = f2bf(v.y); o.z = f2bf(v.z); o.w = f2bf(v.w);
    ((ushort4*)out)[i] = o;
}

// ---------------- fused bf16 MFMA GEMM: [xl | xr] = A @ [Wl;Wr]^T + bias ----------------
// A bf16 [M][K], Wcat bf16 [2*Nhalf][K]. 128x128 tile, BK=64, 4 waves.
// Staging via global_load_lds(16B) with st-style XOR swizzle: linear LDS dest,
// inverse-swizzled global source chunk (ck ^ (row&7)), same XOR on ds_read.
#define GBM 128
#define GBN 128
#define GBK 64

__global__ __launch_bounds__(256) void gemm_fused(const unsigned short* __restrict__ A,
                                                  const unsigned short* __restrict__ Wc,
                                                  const float* __restrict__ bl,
                                                  const float* __restrict__ br,
                                                  unsigned short* __restrict__ outl,
                                                  unsigned short* __restrict__ outr,
                                                  int M, int Nhalf, int K) {
    __shared__ __align__(16) unsigned short Alds[GBM * GBK];
    __shared__ __align__(16) unsigned short Wlds[GBN * GBK];
    const int bm = blockIdx.y * GBM, bn = blockIdx.x * GBN;
    const int tid = threadIdx.x;
    const int lane = tid & 63, wave = tid >> 6;
    const int wr = wave >> 1, wc = wave & 1;       // wave -> 64x64 sub-tile
    const int lrow = lane & 15, kgrp = lane >> 4;  // fragment indices

    f32x4 acc[4][4] = {};

    for (int k0 = 0; k0 < K; k0 += GBK) {
        // stage A and W: 1024 16B chunks each, 4 per thread, direct to LDS
        #pragma unroll
        for (int i = 0; i < 4; ++i) {
            int p = i * 256 + tid;            // chunk id
            int r = p >> 3, ck = p & 7;       // row, chunk-in-row (8 chunks = 64 bf16)
            int sck = ck ^ (r & 7);           // inverse-swizzled source chunk
            int ga = bm + r; ga = (ga < M) ? ga : (M - 1);   // clamp tail (write-guarded)
            unsigned short* la = &Alds[(unsigned)(i * 256 + wave * 64) * 8];
            gload16(A + (size_t)ga * K + k0 + sck * 8, la);
            unsigned short* lw = &Wlds[(unsigned)(i * 256 + wave * 64) * 8];
            gload16(Wc + (size_t)(bn + r) * K + k0 + sck * 8, lw);
        }
        __syncthreads();
        #pragma unroll
        for (int kk = 0; kk < GBK; kk += 32) {
            bf16x8 av[4], bv[4];
            #pragma unroll
            for (int i = 0; i < 4; ++i) {
                int ar = wr * 64 + i * 16 + lrow;
                int ch = ((kk >> 3) + kgrp) ^ (ar & 7);
                av[i] = *(const bf16x8*)(&Alds[ar * GBK + ch * 8]);
            }
            #pragma unroll
            for (int j = 0; j < 4; ++j) {
                int brw = wc * 64 + j * 16 + lrow;
                int ch = ((kk >> 3) + kgrp) ^ (brw & 7);
                bv[j] = *(const bf16x8*)(&Wlds[brw * GBK + ch * 8]);
            }
            #pragma unroll
            for (int i = 0; i < 4; ++i)
                #pragma unroll
                for (int j = 0; j < 4; ++j)
                    acc[i][j] = __builtin_amdgcn_mfma_f32_16x16x32_bf16(av[i], bv[j], acc[i][j], 0, 0, 0);
        }
        __syncthreads();
    }

    // epilogue: C/D layout col=lane&15, row=(lane>>4)*4+reg; block is entirely in one half
    const int half = (bn >= Nhalf) ? 1 : 0;
    unsigned short* outp = half ? outr : outl;
    const float* bp = half ? br : bl;
    const int cb = bn - half * Nhalf;
    #pragma unroll
    for (int j = 0; j < 4; ++j) {
        int col = cb + wc * 64 + j * 16 + lrow;
        float bvv = bp[col];
        #pragma unroll
        for (int i = 0; i < 4; ++i) {
            #pragma unroll
            for (int r = 0; r < 4; ++r) {
                int row = bm + wr * 64 + i * 16 + kgrp * 4 + r;
                if (row < M) outp[(size_t)row * Nhalf + col] = f2bf(acc[i][j][r] + bvv);
            }
        }
    }
}

// ---------------- fused GATv2 edge kernel (bf16 in, 2 channels/thread) ----------------
template <int H, int C, bool DO_ELU, bool DO_RES, bool OUT_F32>
__global__ void gat_edge(const unsigned short* __restrict__ xl,
                         const unsigned short* __restrict__ xr,
                         const float* __restrict__ att, const float* __restrict__ bias,
                         const unsigned short* __restrict__ res, void* __restrict__ outp,
                         const int* __restrict__ row_ptr, const int* __restrict__ csr_src) {
    constexpr int HC = H * C;
    constexpr int T = HC / 2;   // threads per block
    constexpr int RW = C / 2;   // lanes per head
    int n = blockIdx.x;
    int t = threadIdx.x;        // 0..T-1
    ushort2 xru = *(const ushort2*)(xr + (size_t)n * HC + 2 * t);
    float xr0 = bf2f(xru.x), xr1 = bf2f(xru.y);
    float att0 = att[2 * t], att1 = att[2 * t + 1];
    float m = -1e30f, denom = 0.f, acc0 = 0.f, acc1 = 0.f;
    int beg = row_ptr[n], end = row_ptr[n + 1];
    for (int e = beg; e < end; ++e) {
        int s = csr_src[e];
        ushort2 xu = *(const ushort2*)(xl + (size_t)s * HC + 2 * t);
        float x0 = bf2f(xu.x), x1 = bf2f(xu.y);
        float v0 = x0 + xr0; v0 = v0 > 0.f ? v0 : v0 * NEG_SLOPE;
        float v1 = x1 + xr1; v1 = v1 > 0.f ? v1 : v1 * NEG_SLOPE;
        float p = v0 * att0 + v1 * att1;
        #pragma unroll
        for (int mm = RW / 2; mm >= 1; mm >>= 1) p += __shfl_xor(p, mm);
        float mn = fmaxf(m, p);
        float sc = __expf(m - mn), pe = __expf(p - mn);
        denom = denom * sc + pe;
        acc0 = acc0 * sc + pe * x0;
        acc1 = acc1 * sc + pe * x1;
        m = mn;
    }
    float inv = 1.f / denom;  // >=1 edge guaranteed (self loop)
    float o0 = acc0 * inv + bias[2 * t];
    float o1 = acc1 * inv + bias[2 * t + 1];
    if (DO_ELU) {
        o0 = o0 > 0.f ? o0 : __expf(o0) - 1.f;
        o1 = o1 > 0.f ? o1 : __expf(o1) - 1.f;
    }
    if (DO_RES) {
        ushort2 ru = *(const ushort2*)(res + (size_t)n * HC + 2 * t);
        o0 += bf2f(ru.x); o1 += bf2f(ru.y);
    }
    if (OUT_F32) {
        ((float2*)outp)[(size_t)n * T + t] = make_float2(o0, o1);
    } else {
        ushort2 u; u.x = f2bf(o0); u.y = f2bf(o1);
        ((ushort2*)outp)[(size_t)n * T + t] = u;
    }
}

// ---------------- host orchestration ----------------
extern "C" void kernel_launch(void* const* d_in, const int* in_sizes, int n_in,
                              void* d_out, int out_size, void* d_ws, size_t ws_size,
                              hipStream_t stream) {
    const float* x  = (const float*)d_in[0];
    const int*   ei = (const int*)d_in[1];
    auto P = [&](int layer, int j) { return (const float*)d_in[2 + 6 * layer + j]; };

    unsigned short* x_bf = (unsigned short*)d_ws;              // [NN][128]
    unsigned short* h0 = x_bf + (size_t)NN * 128;              // [NN][256]
    unsigned short* h1 = h0 + (size_t)NN * 256;                // [NN][256]
    unsigned short* xl = h1 + (size_t)NN * 256;                // [NN][256]
    unsigned short* xr = xl + (size_t)NN * 256;                // [NN][256]
    unsigned short* Wb = xr + (size_t)NN * 256;                // 393216 bf16 (all weights)
    int* csr_src = (int*)(Wb + 393216);                        // [NE2]
    int* row_ptr = csr_src + NE2;
    int* cursor  = row_ptr + (NN + 1);
    int* deg     = cursor + NN;

    // ---- CSR build ----
    hipMemsetAsync(deg, 0, NN * sizeof(int), stream);
    int eb = (NE2 + 255) / 256;
    count_deg<<<eb, 256, 0, stream>>>(ei, deg);
    scan_deg<<<1, 1024, 0, stream>>>(deg, row_ptr, cursor);
    scatter_edges<<<eb, 256, 0, stream>>>(ei, cursor, csr_src);

    // ---- one-shot conversions ----
    conv_weights<<<384, 256, 0, stream>>>(P(0, 0), P(0, 2), P(1, 0), P(1, 2),
                                          P(2, 0), P(2, 2), P(3, 0), P(3, 2), Wb);
    int n4 = NN * 128 / 4;
    f32_to_bf16<<<(n4 + 255) / 256, 256, 0, stream>>>(x, x_bf, n4);

    dim3 gL(4, (NN + GBM - 1) / GBM);      // Ncat = 512 (xl|xr), layers 0-2
    dim3 gLast(2, (NN + GBM - 1) / GBM);   // Ncat = 256, layer 3

    // ---- Layer 0: 128 -> 8x32, ELU, no residual ----
    gemm_fused<<<gL, 256, 0, stream>>>(x_bf, Wb + 0,      P(0, 1), P(0, 3), xl, xr, NN, 256, 128);
    gat_edge<8, 32, true, false, false><<<NN, 128, 0, stream>>>(xl, xr, P(0, 4), P(0, 5),
                                                                nullptr, h0, row_ptr, csr_src);
    // ---- Layer 1 ----
    gemm_fused<<<gL, 256, 0, stream>>>(h0,   Wb + 65536,  P(1, 1), P(1, 3), xl, xr, NN, 256, 256);
    gat_edge<8, 32, true, true, false><<<NN, 128, 0, stream>>>(xl, xr, P(1, 4), P(1, 5),
                                                               h0, h1, row_ptr, csr_src);
    // ---- Layer 2 ----
    gemm_fused<<<gL, 256, 0, stream>>>(h1,   Wb + 196608, P(2, 1), P(2, 3), xl, xr, NN, 256, 256);
    gat_edge<8, 32, true, true, false><<<NN, 128, 0, stream>>>(xl, xr, P(2, 4), P(2, 5),
                                                               h1, h0, row_ptr, csr_src);
    // ---- Layer 3: 256 -> 1x128, output fp32 ----
    gemm_fused<<<gLast, 256, 0, stream>>>(h0, Wb + 327680, P(3, 1), P(3, 3), xl, xr, NN, 128, 256);
    gat_edge<1, 128, false, false, true><<<NN, 64, 0, stream>>>(xl, xr, P(3, 4), P(3, 5),
                                                                nullptr, d_out, row_ptr, csr_src);
}

// Round 2
// 424.872 us; speedup vs baseline: 1.8129x; 1.3678x over previous
//
#include <hip/hip_runtime.h>
#include <hip/hip_bf16.h>

// ---------------- problem constants ----------------
constexpr int NN = 50000;     // nodes
constexpr int NE = 400000;    // edges (without self loops)
constexpr int NE2 = NE + NN;  // with self loops
constexpr float NEG_SLOPE = 0.2f;

typedef __attribute__((ext_vector_type(8))) __bf16 bf16x8;
typedef __attribute__((ext_vector_type(4))) float f32x4;

__device__ inline float bf2f(unsigned short u) { return __uint_as_float(((unsigned)u) << 16); }
__device__ inline unsigned short f2bf(float f) {
    unsigned x = __float_as_uint(f);
    return (unsigned short)((x + 0x7fffu + ((x >> 16) & 1u)) >> 16);  // RNE
}

__device__ inline void gload16(const unsigned short* g, unsigned short* l) {
    // async global->LDS, 16B per lane; LDS dest is wave-uniform base + lane*16
    __builtin_amdgcn_global_load_lds(
        (const __attribute__((address_space(1))) unsigned int*)(g),
        (__attribute__((address_space(3))) unsigned int*)(l), 16, 0, 0);
}

// ---------------- CSR build ----------------
__global__ void count_deg(const int* __restrict__ ei, int* __restrict__ deg) {
    int e = blockIdx.x * blockDim.x + threadIdx.x;
    if (e >= NE2) return;
    int dst = (e < NE) ? ei[NE + e] : (e - NE);
    atomicAdd(&deg[dst], 1);
}

__global__ __launch_bounds__(1024) void scan_deg(const int* __restrict__ deg,
                                                 int* __restrict__ row_ptr,
                                                 int* __restrict__ cursor) {
    __shared__ int wsum[16];
    int t = threadIdx.x, lane = t & 63, w = t >> 6;
    int carry = 0;
    for (int base = 0; base < NN; base += 1024) {
        int i = base + t;
        int v = (i < NN) ? deg[i] : 0;
        int x = v;
        #pragma unroll
        for (int off = 1; off < 64; off <<= 1) {
            int y = __shfl_up(x, off);
            if (lane >= off) x += y;
        }
        if (lane == 63) wsum[w] = x;
        __syncthreads();
        if (w == 0 && lane < 16) {
            int s = wsum[lane];
            #pragma unroll
            for (int off = 1; off < 16; off <<= 1) {
                int y = __shfl_up(s, off);
                if (lane >= off) s += y;
            }
            wsum[lane] = s;
        }
        __syncthreads();
        int woff = (w == 0) ? 0 : wsum[w - 1];
        int incl = x + woff;
        if (i < NN) {
            int excl = carry + incl - v;
            row_ptr[i] = excl;
            cursor[i] = excl;
        }
        carry += wsum[15];
        __syncthreads();
    }
    if (t == 0) row_ptr[NN] = carry;
}

__global__ void scatter_edges(const int* __restrict__ ei, int* __restrict__ cursor,
                              int* __restrict__ csr_src) {
    int e = blockIdx.x * blockDim.x + threadIdx.x;
    if (e >= NE2) return;
    int src, dst;
    if (e < NE) { src = ei[e]; dst = ei[NE + e]; }
    else        { src = dst = e - NE; }
    int pos = atomicAdd(&cursor[dst], 1);
    csr_src[pos] = src;
}

// ---------------- fp32 -> bf16 convert (x) ----------------
__global__ void f32_to_bf16(const float* __restrict__ in, unsigned short* __restrict__ out, int n4) {
    int i = blockIdx.x * blockDim.x + threadIdx.x;
    if (i >= n4) return;
    float4 v = *(const float4*)(in + 4 * (size_t)i);
    ushort4 o;
    o.x = f2bf(v.x); o.y = f2bf(v.y); o.z = f2bf(v.z); o.w = f2bf(v.w);
    *(ushort4*)(out + 4 * (size_t)i) = o;
}

// ---------------- one-shot weight conversion: all 8 W matrices -> bf16, concatenated ----------------
__global__ void conv_weights(const float* __restrict__ w0l, const float* __restrict__ w0r,
                             const float* __restrict__ w1l, const float* __restrict__ w1r,
                             const float* __restrict__ w2l, const float* __restrict__ w2r,
                             const float* __restrict__ w3l, const float* __restrict__ w3r,
                             unsigned short* __restrict__ out) {
    int i = blockIdx.x * blockDim.x + threadIdx.x;  // float4 index, 0..98303
    const float* src; int base;
    if      (i < 8192)  { src = w0l; base = 0; }
    else if (i < 16384) { src = w0r; base = 8192; }
    else if (i < 32768) { src = w1l; base = 16384; }
    else if (i < 49152) { src = w1r; base = 32768; }
    else if (i < 65536) { src = w2l; base = 49152; }
    else if (i < 81920) { src = w2r; base = 65536; }
    else if (i < 90112) { src = w3l; base = 81920; }
    else                { src = w3r; base = 90112; }
    float4 v = ((const float4*)src)[i - base];
    ushort4 o;
    o.x = f2bf(v.x); o.y = f2bf(v.y); o.z = f2bf(v.z); o.w = f2bf(v.w);
    ((ushort4*)out)[i] = o;
}

// ---------------- fused bf16 MFMA GEMM: [xl | xr] = A @ [Wl;Wr]^T + bias ----------------
// Swapped MFMA operands -> transposed C/D layout: lane holds 4 consecutive out-cols
// per reg -> ushort4 epilogue stores. Bijective XCD swizzle for A-tile L2 reuse.
#define GBM 128
#define GBN 128
#define GBK 64

__global__ __launch_bounds__(256) void gemm_fused(const unsigned short* __restrict__ A,
                                                  const unsigned short* __restrict__ Wc,
                                                  const float* __restrict__ bl,
                                                  const float* __restrict__ br,
                                                  unsigned short* __restrict__ outl,
                                                  unsigned short* __restrict__ outr,
                                                  int M, int Nhalf, int K, int lognx) {
    __shared__ __align__(16) unsigned short Alds[GBM * GBK];
    __shared__ __align__(16) unsigned short Wlds[GBN * GBK];
    // bijective XCD swizzle (m204 variant): consecutive wg within an XCD chunk
    // iterate bx fastest -> blocks sharing an A-tile land on the same XCD L2.
    const int nwg = gridDim.x;
    const int q = nwg >> 3, r8 = nwg & 7;
    const int xcd = blockIdx.x & 7, off = blockIdx.x >> 3;
    const int wg = (xcd < r8 ? xcd * (q + 1) : r8 * (q + 1) + (xcd - r8) * q) + off;
    const int nx = 1 << lognx;
    const int bm = (wg >> lognx) * GBM, bn = (wg & (nx - 1)) * GBN;

    const int tid = threadIdx.x;
    const int lane = tid & 63, wave = tid >> 6;
    const int wr = wave >> 1, wc = wave & 1;       // wave -> 64x64 sub-tile
    const int lrow = lane & 15, kgrp = lane >> 4;  // fragment indices

    f32x4 acc[4][4] = {};

    for (int k0 = 0; k0 < K; k0 += GBK) {
        // stage A and W: 1024 16B chunks each, 4 per thread, direct to LDS
        #pragma unroll
        for (int i = 0; i < 4; ++i) {
            int p = i * 256 + tid;            // chunk id
            int r = p >> 3, ck = p & 7;       // row, chunk-in-row (8 chunks = 64 bf16)
            int sck = ck ^ (r & 7);           // inverse-swizzled source chunk
            int ga = bm + r; ga = (ga < M) ? ga : (M - 1);   // clamp tail (write-guarded)
            unsigned short* la = &Alds[(unsigned)(i * 256 + wave * 64) * 8];
            gload16(A + (size_t)ga * K + k0 + sck * 8, la);
            unsigned short* lw = &Wlds[(unsigned)(i * 256 + wave * 64) * 8];
            gload16(Wc + (size_t)(bn + r) * K + k0 + sck * 8, lw);
        }
        __syncthreads();
        #pragma unroll
        for (int kk = 0; kk < GBK; kk += 32) {
            bf16x8 av[4], bv[4];
            #pragma unroll
            for (int i = 0; i < 4; ++i) {
                int ar = wr * 64 + i * 16 + lrow;
                int ch = ((kk >> 3) + kgrp) ^ (ar & 7);
                av[i] = *(const bf16x8*)(&Alds[ar * GBK + ch * 8]);
            }
            #pragma unroll
            for (int j = 0; j < 4; ++j) {
                int brw = wc * 64 + j * 16 + lrow;
                int ch = ((kk >> 3) + kgrp) ^ (brw & 7);
                bv[j] = *(const bf16x8*)(&Wlds[brw * GBK + ch * 8]);
            }
            // swapped operands: D row-dim <- bv (out cols), col-dim <- av (out rows)
            #pragma unroll
            for (int i = 0; i < 4; ++i)
                #pragma unroll
                for (int j = 0; j < 4; ++j)
                    acc[i][j] = __builtin_amdgcn_mfma_f32_16x16x32_bf16(bv[j], av[i], acc[i][j], 0, 0, 0);
        }
        __syncthreads();
    }

    // epilogue: lane holds out[row = bm+wr*64+i*16+lrow][col = cb+j*16+kgrp*4+r], r=0..3
    const int half = (bn >= Nhalf) ? 1 : 0;
    unsigned short* outp = half ? outr : outl;
    const float* bp = half ? br : bl;
    const int cb = bn - half * Nhalf + wc * 64;
    #pragma unroll
    for (int i = 0; i < 4; ++i) {
        int row = bm + wr * 64 + i * 16 + lrow;
        if (row < M) {
            #pragma unroll
            for (int j = 0; j < 4; ++j) {
                int col = cb + j * 16 + kgrp * 4;
                float4 bb = *(const float4*)(bp + col);
                ushort4 o;
                o.x = f2bf(acc[i][j][0] + bb.x);
                o.y = f2bf(acc[i][j][1] + bb.y);
                o.z = f2bf(acc[i][j][2] + bb.z);
                o.w = f2bf(acc[i][j][3] + bb.w);
                *(ushort4*)(outp + (size_t)row * Nhalf + col) = o;
            }
        }
    }
}

// ---------------- fused GATv2 edge kernel ----------------
// VEC channels/thread, NW edge-split slices of T=HC/VEC lanes, online-softmax
// merge via LDS, pairwise-unrolled edge loop (one combined update per 2 edges).
template <int H, int C, int VEC, int NW, bool DO_ELU, bool DO_RES, bool OUT_F32>
__global__ __launch_bounds__(128) void gat_edge(
        const unsigned short* __restrict__ xl,
        const unsigned short* __restrict__ xr,
        const float* __restrict__ att, const float* __restrict__ bias,
        const unsigned short* __restrict__ res, void* __restrict__ outp,
        const int* __restrict__ row_ptr, const int* __restrict__ csr_src) {
    constexpr int HC = H * C;
    constexpr int T = HC / VEC;    // lanes per slice
    constexpr int RW = C / VEC;    // lanes per head (shfl-reduce group)
    __shared__ float smem[NW * T * (2 + VEC)];
    const int n = blockIdx.x;
    const int w = threadIdx.x / T;       // slice id
    const int t = threadIdx.x % T;       // lane within slice
    const int ch = VEC * t;
    const size_t base_r = (size_t)n * HC + ch;

    float xrv[VEC], av[VEC];
    if constexpr (VEC == 4) {
        ushort4 u = *(const ushort4*)(xr + base_r);
        xrv[0] = bf2f(u.x); xrv[1] = bf2f(u.y); xrv[2] = bf2f(u.z); xrv[3] = bf2f(u.w);
        float4 a4 = *(const float4*)(att + ch);
        av[0] = a4.x; av[1] = a4.y; av[2] = a4.z; av[3] = a4.w;
    } else {
        ushort2 u = *(const ushort2*)(xr + base_r);
        xrv[0] = bf2f(u.x); xrv[1] = bf2f(u.y);
        float2 a2 = *(const float2*)(att + ch);
        av[0] = a2.x; av[1] = a2.y;
    }

    float m = -1e30f, d = 0.f, acc[VEC];
    #pragma unroll
    for (int v = 0; v < VEC; ++v) acc[v] = 0.f;

    const int beg = row_ptr[n], end = row_ptr[n + 1];
    int e = beg + w;
    for (; e + NW < end; e += 2 * NW) {
        int s0 = csr_src[e], s1 = csr_src[e + NW];
        float x0[VEC], x1[VEC];
        if constexpr (VEC == 4) {
            ushort4 u0 = *(const ushort4*)(xl + (size_t)s0 * HC + ch);
            ushort4 u1 = *(const ushort4*)(xl + (size_t)s1 * HC + ch);
            x0[0] = bf2f(u0.x); x0[1] = bf2f(u0.y); x0[2] = bf2f(u0.z); x0[3] = bf2f(u0.w);
            x1[0] = bf2f(u1.x); x1[1] = bf2f(u1.y); x1[2] = bf2f(u1.z); x1[3] = bf2f(u1.w);
        } else {
            ushort2 u0 = *(const ushort2*)(xl + (size_t)s0 * HC + ch);
            ushort2 u1 = *(const ushort2*)(xl + (size_t)s1 * HC + ch);
            x0[0] = bf2f(u0.x); x0[1] = bf2f(u0.y);
            x1[0] = bf2f(u1.x); x1[1] = bf2f(u1.y);
        }
        float p0 = 0.f, p1 = 0.f;
        #pragma unroll
        for (int v = 0; v < VEC; ++v) {
            float u0 = x0[v] + xrv[v]; u0 = fmaxf(u0, u0 * NEG_SLOPE);
            float u1 = x1[v] + xrv[v]; u1 = fmaxf(u1, u1 * NEG_SLOPE);
            p0 = fmaf(u0, av[v], p0);
            p1 = fmaf(u1, av[v], p1);
        }
        #pragma unroll
        for (int mm = RW / 2; mm >= 1; mm >>= 1) {
            p0 += __shfl_xor(p0, mm);
            p1 += __shfl_xor(p1, mm);
        }
        float mn = fmaxf(m, fmaxf(p0, p1));
        float sc = __expf(m - mn), e0 = __expf(p0 - mn), e1 = __expf(p1 - mn);
        d = d * sc + e0 + e1;
        #pragma unroll
        for (int v = 0; v < VEC; ++v)
            acc[v] = fmaf(acc[v], sc, fmaf(e0, x0[v], e1 * x1[v]));
        m = mn;
    }
    if (e < end) {  // tail edge (at most one per slice)
        int s0 = csr_src[e];
        float x0[VEC];
        if constexpr (VEC == 4) {
            ushort4 u0 = *(const ushort4*)(xl + (size_t)s0 * HC + ch);
            x0[0] = bf2f(u0.x); x0[1] = bf2f(u0.y); x0[2] = bf2f(u0.z); x0[3] = bf2f(u0.w);
        } else {
            ushort2 u0 = *(const ushort2*)(xl + (size_t)s0 * HC + ch);
            x0[0] = bf2f(u0.x); x0[1] = bf2f(u0.y);
        }
        float p0 = 0.f;
        #pragma unroll
        for (int v = 0; v < VEC; ++v) {
            float u0 = x0[v] + xrv[v]; u0 = fmaxf(u0, u0 * NEG_SLOPE);
            p0 = fmaf(u0, av[v], p0);
        }
        #pragma unroll
        for (int mm = RW / 2; mm >= 1; mm >>= 1) p0 += __shfl_xor(p0, mm);
        float mn = fmaxf(m, p0);
        float sc = __expf(m - mn), e0 = __expf(p0 - mn);
        d = d * sc + e0;
        #pragma unroll
        for (int v = 0; v < VEC; ++v) acc[v] = fmaf(acc[v], sc, e0 * x0[v]);
        m = mn;
    }

    // cross-slice online-softmax merge via LDS
    float* st = &smem[(w * T + t) * (2 + VEC)];
    st[0] = m; st[1] = d;
    #pragma unroll
    for (int v = 0; v < VEC; ++v) st[2 + v] = acc[v];
    __syncthreads();
    if (w == 0) {
        #pragma unroll
        for (int o = 1; o < NW; ++o) {
            const float* so = &smem[(o * T + t) * (2 + VEC)];
            float mo = so[0], dd = so[1];
            float mn = fmaxf(m, mo);
            float s0 = __expf(m - mn), s1 = __expf(mo - mn);
            d = d * s0 + dd * s1;
            #pragma unroll
            for (int v = 0; v < VEC; ++v) acc[v] = acc[v] * s0 + so[2 + v] * s1;
            m = mn;
        }
        float inv = 1.f / d;  // >=1 edge guaranteed (self loop in slice 0)
        float o_[VEC];
        if constexpr (VEC == 4) {
            float4 b4 = *(const float4*)(bias + ch);
            o_[0] = acc[0] * inv + b4.x; o_[1] = acc[1] * inv + b4.y;
            o_[2] = acc[2] * inv + b4.z; o_[3] = acc[3] * inv + b4.w;
        } else {
            float2 b2 = *(const float2*)(bias + ch);
            o_[0] = acc[0] * inv + b2.x; o_[1] = acc[1] * inv + b2.y;
        }
        if constexpr (DO_ELU) {
            #pragma unroll
            for (int v = 0; v < VEC; ++v) o_[v] = o_[v] > 0.f ? o_[v] : __expf(o_[v]) - 1.f;
        }
        if constexpr (DO_RES) {
            if constexpr (VEC == 4) {
                ushort4 ru = *(const ushort4*)(res + base_r);
                o_[0] += bf2f(ru.x); o_[1] += bf2f(ru.y); o_[2] += bf2f(ru.z); o_[3] += bf2f(ru.w);
            } else {
                ushort2 ru = *(const ushort2*)(res + base_r);
                o_[0] += bf2f(ru.x); o_[1] += bf2f(ru.y);
            }
        }
        if constexpr (OUT_F32) {
            if constexpr (VEC == 4)
                *(float4*)((float*)outp + base_r) = make_float4(o_[0], o_[1], o_[2], o_[3]);
            else
                *(float2*)((float*)outp + base_r) = make_float2(o_[0], o_[1]);
        } else {
            if constexpr (VEC == 4) {
                ushort4 u;
                u.x = f2bf(o_[0]); u.y = f2bf(o_[1]); u.z = f2bf(o_[2]); u.w = f2bf(o_[3]);
                *(ushort4*)((unsigned short*)outp + base_r) = u;
            } else {
                ushort2 u;
                u.x = f2bf(o_[0]); u.y = f2bf(o_[1]);
                *(ushort2*)((unsigned short*)outp + base_r) = u;
            }
        }
    }
}

// ---------------- host orchestration ----------------
extern "C" void kernel_launch(void* const* d_in, const int* in_sizes, int n_in,
                              void* d_out, int out_size, void* d_ws, size_t ws_size,
                              hipStream_t stream) {
    const float* x  = (const float*)d_in[0];
    const int*   ei = (const int*)d_in[1];
    auto P = [&](int layer, int j) { return (const float*)d_in[2 + 6 * layer + j]; };

    unsigned short* x_bf = (unsigned short*)d_ws;              // [NN][128]
    unsigned short* h0 = x_bf + (size_t)NN * 128;              // [NN][256]
    unsigned short* h1 = h0 + (size_t)NN * 256;                // [NN][256]
    unsigned short* xl = h1 + (size_t)NN * 256;                // [NN][256]
    unsigned short* xr = xl + (size_t)NN * 256;                // [NN][256]
    unsigned short* Wb = xr + (size_t)NN * 256;                // 393216 bf16 (all weights)
    int* csr_src = (int*)(Wb + 393216);                        // [NE2]
    int* row_ptr = csr_src + NE2;
    int* cursor  = row_ptr + (NN + 1);
    int* deg     = cursor + NN;

    // ---- CSR build ----
    hipMemsetAsync(deg, 0, NN * sizeof(int), stream);
    int eb = (NE2 + 255) / 256;
    count_deg<<<eb, 256, 0, stream>>>(ei, deg);
    scan_deg<<<1, 1024, 0, stream>>>(deg, row_ptr, cursor);
    scatter_edges<<<eb, 256, 0, stream>>>(ei, cursor, csr_src);

    // ---- one-shot conversions ----
    conv_weights<<<384, 256, 0, stream>>>(P(0, 0), P(0, 2), P(1, 0), P(1, 2),
                                          P(2, 0), P(2, 2), P(3, 0), P(3, 2), Wb);
    int n4 = NN * 128 / 4;
    f32_to_bf16<<<(n4 + 255) / 256, 256, 0, stream>>>(x, x_bf, n4);

    const int mb = (NN + GBM - 1) / GBM;     // 391
    const int nwgL = 4 * mb, nwgLast = 2 * mb;

    // ---- Layer 0: 128 -> 8x32, ELU, no residual ----
    gemm_fused<<<nwgL, 256, 0, stream>>>(x_bf, Wb + 0,      P(0, 1), P(0, 3), xl, xr, NN, 256, 128, 2);
    gat_edge<8, 32, 4, 2, true, false, false><<<NN, 128, 0, stream>>>(xl, xr, P(0, 4), P(0, 5),
                                                                      nullptr, h0, row_ptr, csr_src);
    // ---- Layer 1 ----
    gemm_fused<<<nwgL, 256, 0, stream>>>(h0,   Wb + 65536,  P(1, 1), P(1, 3), xl, xr, NN, 256, 256, 2);
    gat_edge<8, 32, 4, 2, true, true, false><<<NN, 128, 0, stream>>>(xl, xr, P(1, 4), P(1, 5),
                                                                     h0, h1, row_ptr, csr_src);
    // ---- Layer 2 ----
    gemm_fused<<<nwgL, 256, 0, stream>>>(h1,   Wb + 196608, P(2, 1), P(2, 3), xl, xr, NN, 256, 256, 2);
    gat_edge<8, 32, 4, 2, true, true, false><<<NN, 128, 0, stream>>>(xl, xr, P(2, 4), P(2, 5),
                                                                     h1, h0, row_ptr, csr_src);
    // ---- Layer 3: 256 -> 1x128, output fp32 ----
    gemm_fused<<<nwgLast, 256, 0, stream>>>(h0, Wb + 327680, P(3, 1), P(3, 3), xl, xr, NN, 128, 256, 1);
    gat_edge<1, 128, 4, 4, false, false, true><<<NN, 128, 0, stream>>>(xl, xr, P(3, 4), P(3, 5),
                                                                       nullptr, d_out, row_ptr, csr_src);
}